// Round 2
// 2126.261 us; speedup vs baseline: 1.0242x; 1.0242x over previous
//
#include <hip/hip_runtime.h>

// Problem constants (fixed by the reference)
#define DD   300     // emb dim
#define DD2  600     // 2*D
#define GG   4000    // graphs
#define GPAD 4096    // padded graph count (multiple of 64)
#define LL   5       // layers
#define BN_EPS 1e-5f

typedef float f32x4  __attribute__((ext_vector_type(4)));
typedef short bf16x8 __attribute__((ext_vector_type(8)));

__device__ __forceinline__ unsigned short f2bf(float f) {
    unsigned int x = __float_as_uint(f);
    unsigned int r = (x + 0x7FFFu + ((x >> 16) & 1u)) >> 16;   // RTNE
    return (unsigned short)r;
}

// ---------------------------------------------------------------- histogram
__global__ __launch_bounds__(256) void k_hist(const int* __restrict__ idx, int* __restrict__ cnt, int n) {
    int i = blockIdx.x * 256 + threadIdx.x;
    if (i < n) atomicAdd(&cnt[idx[i]], 1);
}

// ---------------------------------------------------------------- hierarchical exclusive scan
__global__ __launch_bounds__(256) void k_scan1(const int* __restrict__ in, int* __restrict__ bsum, int n) {
    int t = threadIdx.x;
    int i = blockIdx.x * 256 + t;
    int v = (i < n) ? in[i] : 0;
    for (int off = 32; off >= 1; off >>= 1) v += __shfl_down(v, off, 64);
    __shared__ int s[4];
    if ((t & 63) == 0) s[t >> 6] = v;
    __syncthreads();
    if (t == 0) bsum[blockIdx.x] = s[0] + s[1] + s[2] + s[3];
}
__global__ __launch_bounds__(1024) void k_scan2(int* __restrict__ bsum, int nb) {
    __shared__ int s[1024];
    int t = threadIdx.x;
    int v = (t < nb) ? bsum[t] : 0;
    s[t] = v;
    __syncthreads();
    for (int off = 1; off < 1024; off <<= 1) {
        int u = (t >= off) ? s[t - off] : 0;
        __syncthreads();
        s[t] += u;
        __syncthreads();
    }
    if (t < nb) bsum[t] = s[t] - v;   // exclusive
}
__global__ __launch_bounds__(256) void k_scan3(const int* __restrict__ in, const int* __restrict__ boff,
                                               int* __restrict__ out, int n, int total) {
    __shared__ int s[256];
    int t = threadIdx.x;
    int i = blockIdx.x * 256 + t;
    int v = (i < n) ? in[i] : 0;
    s[t] = v;
    __syncthreads();
    for (int off = 1; off < 256; off <<= 1) {
        int u = (t >= off) ? s[t - off] : 0;
        __syncthreads();
        s[t] += u;
        __syncthreads();
    }
    if (i < n) out[i] = boff[blockIdx.x] + s[t] - v;
    if (i == 0) out[n] = total;
}

// place edges grouped by dst; einfo = src | (code<<20), code = type*3+dir
__global__ __launch_bounds__(256) void k_place(const int* __restrict__ src, const int* __restrict__ dst,
                                               const int* __restrict__ ety, const int* __restrict__ edir,
                                               const int* __restrict__ rowptr, int* __restrict__ cursor,
                                               int* __restrict__ einfo, int E) {
    int e = blockIdx.x * 256 + threadIdx.x;
    if (e >= E) return;
    int d = dst[e];
    int pos = rowptr[d] + atomicAdd(&cursor[d], 1);
    einfo[pos] = src[e] | ((ety[e] * 3 + edir[e]) << 20);
}

// ---------------------------------------------------------------- comb tables
__global__ __launch_bounds__(256) void k_comb(const float* __restrict__ e1, const float* __restrict__ e2,
                                              float* __restrict__ comb) {
    int c = blockIdx.x, l = blockIdx.y;
    const float* r1 = e1 + ((size_t)l * 6 + (c / 3)) * DD;
    const float* r2 = e2 + ((size_t)l * 3 + (c % 3)) * DD;
    float* out = comb + ((size_t)l * 18 + c) * DD;
    for (int d = threadIdx.x; d < DD; d += 256) out[d] = r1[d] + r2[d];
}

// ---------------------------------------------------------------- h init
__global__ __launch_bounds__(256) void k_init_h(const int* __restrict__ xa, const int* __restrict__ xc,
                                                const float* __restrict__ emb1, const float* __restrict__ emb2,
                                                const float* __restrict__ vne,
                                                float* __restrict__ h, int N) {
    int n = blockIdx.x;
    if (n >= N) return;
    int a = xa[n], c = xc[n];
    for (int d = threadIdx.x; d < DD; d += 256)
        h[(size_t)n * DD + d] = emb1[(size_t)a * DD + d] + emb2[(size_t)c * DD + d] + vne[d];
}

__global__ __launch_bounds__(256) void k_init_vn(const float* __restrict__ vne, float* __restrict__ vnh) {
    int g = blockIdx.x;
    for (int d = threadIdx.x; d < DD; d += 256) vnh[(size_t)g * DD + d] = vne[d];
}

// ---------------------------------------------------------------- fused aggregation (CSR gather)
__global__ __launch_bounds__(256) void k_aggr(const float* __restrict__ h,
                                              const int* __restrict__ rowptr, const int* __restrict__ einfo,
                                              const float* __restrict__ comb,
                                              const int* __restrict__ batch, const float* __restrict__ vnh,
                                              int use_vn,
                                              unsigned short* __restrict__ aggrb, int N, int Npad) {
    const int node = blockIdx.x * 4 + (threadIdx.x >> 6);
    const int lane = threadIdx.x & 63;
    if (node >= Npad) return;
    unsigned short* out = aggrb + (size_t)node * 320;
    if (node >= N) {
#pragma unroll
        for (int j = 0; j < 5; j++) out[lane + 64 * j] = 0;
        return;
    }
    float acc[5];
    const float* sc = comb + 12 * DD;   // self-loop: type 4, dir 0
    const int p0 = rowptr[node], p1 = rowptr[node + 1];
    if (use_vn) {
        {
            const float* hs = h + (size_t)node * DD;
            const float* vs = vnh + (size_t)batch[node] * DD;
#pragma unroll
            for (int j = 0; j < 5; j++) {
                int d = lane + 64 * j;
                acc[j] = (d < DD) ? hs[d] + sc[d] + vs[d] : 0.f;
            }
        }
        for (int p = p0; p < p1; p++) {
            int info = einfo[p];
            int s = info & 0xFFFFF;
            const float* hr = h + (size_t)s * DD;
            const float* cr = comb + (size_t)(info >> 20) * DD;
            const float* vr = vnh + (size_t)batch[s] * DD;
#pragma unroll
            for (int j = 0; j < 5; j++) {
                int d = lane + 64 * j;
                if (d < DD) acc[j] += hr[d] + cr[d] + vr[d];
            }
        }
    } else {
        {
            const float* hs = h + (size_t)node * DD;
#pragma unroll
            for (int j = 0; j < 5; j++) {
                int d = lane + 64 * j;
                acc[j] = (d < DD) ? hs[d] + sc[d] : 0.f;
            }
        }
        for (int p = p0; p < p1; p++) {
            int info = einfo[p];
            const float* hr = h + (size_t)(info & 0xFFFFF) * DD;
            const float* cr = comb + (size_t)(info >> 20) * DD;
#pragma unroll
            for (int j = 0; j < 5; j++) {
                int d = lane + 64 * j;
                if (d < DD) acc[j] += hr[d] + cr[d];
            }
        }
    }
#pragma unroll
    for (int j = 0; j < 5; j++) {
        int d = lane + 64 * j;
        out[d] = (d < DD) ? f2bf(acc[j]) : (unsigned short)0;
    }
}

// ------------------------------------------- weight transpose+pad -> bf16
__global__ __launch_bounds__(256) void k_convw(const float* __restrict__ w, short* __restrict__ wt,
                                               int K, int Nn, int KP, int NP) {
    int n = blockIdx.x;
    int l = blockIdx.y;
    const float* wl = w + (size_t)l * K * Nn;
    short* wtl = wt + (size_t)l * NP * KP;
    for (int k = threadIdx.x; k < KP; k += 256) {
        float v = (k < K && n < Nn) ? wl[(size_t)k * Nn + n] : 0.f;
        wtl[(size_t)n * KP + k] = (short)f2bf(v);
    }
}

__global__ __launch_bounds__(256) void k_padb(const float* __restrict__ b, float* __restrict__ bp) {
    int l = blockIdx.y;
    int n = blockIdx.x * 256 + threadIdx.x;
    if (n < 640) bp[(size_t)l * 640 + n] = (n < DD2) ? b[(size_t)l * DD2 + n] : 0.f;
}

// ------------------------------------------- fused MLP (MFMA bf16)
// h = BN(relu(aggrb @ W1^T + b1) @ W2^T + b2) (+ReLU)
// Per block: 64 rows. A tile held in REGISTERS (10 bf16x8/lane, loaded once).
// hidden computed in 4 chunks of 160 cols into LDS (sH), each chunk immediately
// consumed as a K-slice of the second GEMM. Weight chunks double-buffered in sB.

// cooperative 160x32 bf16 weight-chunk load (640 x 16B), matches sB[160][40] staging
#define LD3(PTR, STRIDE, ROWBASE, KOFF)                                                                     \
    do {                                                                                                    \
        v0 = *(const float4*)((PTR) + (size_t)((ROWBASE) + (t >> 2)) * (STRIDE) + (KOFF) + (t & 3) * 8);    \
        v1 = *(const float4*)((PTR) + (size_t)((ROWBASE) + (t >> 2) + 64) * (STRIDE) + (KOFF) + (t & 3) * 8); \
        if (t < 128)                                                                                        \
            v2 = *(const float4*)((PTR) + (size_t)((ROWBASE) + (t >> 2) + 128) * (STRIDE) + (KOFF) + (t & 3) * 8); \
    } while (0)

#define ST3(BUF)                                                    \
    do {                                                            \
        *(float4*)&sB[BUF][t >> 2][(t & 3) * 8] = v0;               \
        *(float4*)&sB[BUF][(t >> 2) + 64][(t & 3) * 8] = v1;        \
        if (t < 128) *(float4*)&sB[BUF][(t >> 2) + 128][(t & 3) * 8] = v2; \
    } while (0)

__global__ __launch_bounds__(256, 2) void k_mlp(const unsigned short* __restrict__ aggrb, // [Npad][320] bf16
                                                const short* __restrict__ w1t,            // [640][320] bf16
                                                const float* __restrict__ b1p,            // [640]
                                                const short* __restrict__ w2t,            // [320][640] bf16
                                                const float* __restrict__ b2,
                                                const float* __restrict__ bng, const float* __restrict__ bnb,
                                                const float* __restrict__ bnm, const float* __restrict__ bnv,
                                                float* __restrict__ h, int N, int relu_out) {
    __shared__ short sH[64][168];      // hidden chunk [64][160], padded stride
    __shared__ short sB[2][160][40];   // weight chunk staging (proven padded layout)

    const int t    = threadIdx.x;
    const int m0   = blockIdx.x * 64;
    const int lane = t & 63;
    const int w    = t >> 6;
    const int col  = lane & 15;
    const int kq   = lane >> 4;        // 0..3
    const int kb   = kq << 3;
    const int mrow = (w << 4) + col;

    // ---- prologue: A fragments -> registers (each element loaded exactly once per block);
    //      W1 chunk (ch=0, ks=0) -> sB[0]
    bf16x8 areg[10];
    {
        const unsigned short* ap = aggrb + (size_t)(m0 + mrow) * 320 + kb;
#pragma unroll
        for (int ks = 0; ks < 10; ks++)
            areg[ks] = *(const bf16x8*)(ap + ks * 32);
        float4 v0, v1, v2;
        LD3(w1t, 320, 0, 0);
        ST3(0);
    }
    __syncthreads();

    f32x4 zacc[20];
#pragma unroll
    for (int j = 0; j < 20; j++) zacc[j] = (f32x4){0.f, 0.f, 0.f, 0.f};

    for (int ch = 0; ch < 4; ch++) {
        f32x4 hacc[10];
#pragma unroll
        for (int j = 0; j < 10; j++) hacc[j] = (f32x4){0.f, 0.f, 0.f, 0.f};

        // ---- phase A: hidden[64][ch*160 .. +160) = relu(A @ W1 + b1), K=320 in 10 steps
#pragma unroll
        for (int ks = 0; ks < 10; ks++) {
            float4 v0, v1, v2;
            if (ks < 9) LD3(w1t, 320, ch * 160, (ks + 1) * 32);   // next W1 chunk
            else        LD3(w2t, 640, 0, ch * 160);               // prefetch phase-B step 0 (half 0, ks2 0)
#pragma unroll
            for (int nt = 0; nt < 10; nt++) {
                bf16x8 b = *(const bf16x8*)&sB[ks & 1][(nt << 4) + col][kb];
                hacc[nt] = __builtin_amdgcn_mfma_f32_16x16x32_bf16(areg[ks], b, hacc[nt], 0, 0, 0);
            }
            ST3((ks & 1) ^ 1);
            if (ks == 9) {
                // finalize hidden chunk into LDS (bias + relu + bf16), before the barrier
#pragma unroll
                for (int nt = 0; nt < 10; nt++) {
                    float bias = b1p[ch * 160 + (nt << 4) + col];
#pragma unroll
                    for (int r = 0; r < 4; r++)
                        sH[(w << 4) + (kq << 2) + r][(nt << 4) + col] =
                            (short)f2bf(fmaxf(hacc[nt][r] + bias, 0.f));
                }
            }
            __syncthreads();
        }

        // ---- phase B: zacc += hidden_chunk @ W2(k = ch*160..+160), 5 k-steps x 2 col-halves
#pragma unroll
        for (int s = 0; s < 10; s++) {
            const int ks2 = s >> 1, half = s & 1;
            float4 v0, v1, v2;
            bool stage = true;
            if (s < 9)       LD3(w2t, 640, ((s + 1) & 1) * 160, ch * 160 + ((s + 1) >> 1) * 32);
            else if (ch < 3) LD3(w1t, 320, (ch + 1) * 160, 0);    // next chunk phase-A step 0
            else stage = false;
            bf16x8 a = *(const bf16x8*)&sH[mrow][ks2 * 32 + kb];
#pragma unroll
            for (int jt = 0; jt < 10; jt++) {
                bf16x8 b = *(const bf16x8*)&sB[s & 1][(jt << 4) + col][kb];
                zacc[half * 10 + jt] = __builtin_amdgcn_mfma_f32_16x16x32_bf16(a, b, zacc[half * 10 + jt], 0, 0, 0);
            }
            if (stage) ST3((s & 1) ^ 1);
            __syncthreads();
        }
    }

    // ---- epilogue: bias + BN (+ReLU) -> h f32
#pragma unroll
    for (int j = 0; j < 20; j++) {
        int n = (j << 4) + col;
        if (n < DD) {
            float bz = b2[n];
            float sc = bng[n] * rsqrtf(bnv[n] + BN_EPS);
            float mB = bnm[n], bB = bnb[n];
            int mbase = m0 + (w << 4) + (kq << 2);
#pragma unroll
            for (int r = 0; r < 4; r++) {
                int m = mbase + r;
                if (m < N) {
                    float z = (zacc[j][r] + bz - mB) * sc + bB;
                    if (relu_out) z = fmaxf(z, 0.f);
                    h[(size_t)m * DD + n] = z;
                }
            }
        }
    }
}

// ------------------------------------------- mean-pool + vnh add -> bf16 vnin[G][320]
__global__ __launch_bounds__(256) void k_pool2(const float* __restrict__ h, const int* __restrict__ gptr,
                                               const float* __restrict__ vnh,
                                               unsigned short* __restrict__ vnin) {
    int g = blockIdx.x, t = threadIdx.x;
    const int gs = gptr[g], ge = gptr[g + 1];
    const float inv = 1.0f / fmaxf((float)(ge - gs), 1.0f);
    const int j0 = t, j1 = t + 256;
    const bool g1 = (j1 < DD);
    float a0 = 0.f, a1 = 0.f;
    for (int n = gs; n < ge; n++) {
        a0 += h[(size_t)n * DD + j0];
        if (g1) a1 += h[(size_t)n * DD + j1];
    }
    vnin[(size_t)g * 320 + j0] = f2bf(a0 * inv + vnh[(size_t)g * DD + j0]);
    if (j1 < 320)
        vnin[(size_t)g * 320 + j1] = g1 ? f2bf(a1 * inv + vnh[(size_t)g * DD + j1]) : (unsigned short)0;
}

// ------------------------------------------- VN GEMM (MFMA bf16), M=GPAD, N=320, K=320
__global__ __launch_bounds__(256) void k_vng(const unsigned short* __restrict__ A,   // [GPAD][320] bf16
                                             const short* __restrict__ Wt,           // [320][320] bf16
                                             const float* __restrict__ bias,         // [300]
                                             float* __restrict__ outf,               // [G][300] f32
                                             int M) {
    __shared__ short sA[2][64][40];
    __shared__ short sB[2][160][40];
    const int t  = threadIdx.x;
    const int m0 = blockIdx.x * 64;
    const int n0 = blockIdx.y * 160;
    const int ar = t >> 2, aq = (t & 3) << 3;

    {
        *(float4*)&sA[0][ar][aq] = *(const float4*)(A + (size_t)(m0 + ar) * 320 + aq);
#pragma unroll
        for (int i = 0; i < 3; i++) {
            int c = t + (i << 8);
            if (c < 640) {
                int br = c >> 2, bq = (c & 3) << 3;
                *(float4*)&sB[0][br][bq] = *(const float4*)(Wt + (size_t)(n0 + br) * 320 + bq);
            }
        }
    }
    __syncthreads();

    const int lane = t & 63;
    const int w    = t >> 6;
    const int mrow = (w << 4) + (lane & 15);
    const int kb   = (lane >> 4) << 3;
    const int col  = lane & 15;
    const int rq   = (lane >> 4) << 2;

    f32x4 acc[10];
#pragma unroll
    for (int nt = 0; nt < 10; nt++) acc[nt] = (f32x4){0.f, 0.f, 0.f, 0.f};

    for (int ks = 0; ks < 10; ks++) {
        const int nb = ks & 1;
        const bool have = (ks + 1) < 10;
        float4 avr, bv0, bv1, bv2;
        if (have) {
            const int k0 = (ks + 1) << 5;
            avr = *(const float4*)(A + (size_t)(m0 + ar) * 320 + k0 + aq);
            int c = t;
            bv0 = *(const float4*)(Wt + (size_t)(n0 + (c >> 2)) * 320 + k0 + ((c & 3) << 3));
            c = t + 256;
            bv1 = *(const float4*)(Wt + (size_t)(n0 + (c >> 2)) * 320 + k0 + ((c & 3) << 3));
            if (t < 128) {
                c = t + 512;
                bv2 = *(const float4*)(Wt + (size_t)(n0 + (c >> 2)) * 320 + k0 + ((c & 3) << 3));
            }
        }
        bf16x8 a = *(const bf16x8*)&sA[nb][mrow][kb];
#pragma unroll
        for (int nt = 0; nt < 10; nt++) {
            bf16x8 b = *(const bf16x8*)&sB[nb][(nt << 4) + col][kb];
            acc[nt] = __builtin_amdgcn_mfma_f32_16x16x32_bf16(a, b, acc[nt], 0, 0, 0);
        }
        if (have) {
            *(float4*)&sA[nb ^ 1][ar][aq] = avr;
            int c = t;
            *(float4*)&sB[nb ^ 1][c >> 2][(c & 3) << 3] = bv0;
            c = t + 256;
            *(float4*)&sB[nb ^ 1][c >> 2][(c & 3) << 3] = bv1;
            if (t < 128) {
                c = t + 512;
                *(float4*)&sB[nb ^ 1][c >> 2][(c & 3) << 3] = bv2;
            }
        }
        __syncthreads();
    }

#pragma unroll
    for (int nt = 0; nt < 10; nt++) {
        int n = n0 + (nt << 4) + col;
        bool nok = (n < DD);
        float bz = nok ? bias[n] : 0.f;
        int mbase = m0 + (w << 4) + rq;
#pragma unroll
        for (int r = 0; r < 4; r++) {
            int m = mbase + r;
            if (nok && m < M)
                outf[(size_t)m * DD + n] = acc[nt][r] + bz;
        }
    }
}

// ------------------------------------------- row LayerNorm + ReLU -> bf16 [G][320]
__global__ __launch_bounds__(256) void k_ln(const float* __restrict__ tbuf,   // [G][300]
                                            const float* __restrict__ lng, const float* __restrict__ lnb,
                                            unsigned short* __restrict__ vnrelu) {
    __shared__ float rs[4], rq[4];
    __shared__ float s_mu, s_rstd;
    int g = blockIdx.x, t = threadIdx.x;
    const int j0 = t, j1 = t + 256;
    const bool g1 = (j1 < DD);
    float t0 = tbuf[(size_t)g * DD + j0];
    float t1 = g1 ? tbuf[(size_t)g * DD + j1] : 0.f;
    float ps = t0 + t1;
    float pq = t0 * t0 + t1 * t1;
    for (int off = 32; off >= 1; off >>= 1) { ps += __shfl_down(ps, off, 64); pq += __shfl_down(pq, off, 64); }
    int wid = t >> 6, lane = t & 63;
    if (lane == 0) { rs[wid] = ps; rq[wid] = pq; }
    __syncthreads();
    if (t == 0) {
        float S = rs[0] + rs[1] + rs[2] + rs[3];
        float Q = rq[0] + rq[1] + rq[2] + rq[3];
        float mu = S / DD;
        float var = Q / DD - mu * mu;
        s_mu = mu;
        s_rstd = rsqrtf(var + BN_EPS);
    }
    __syncthreads();
    float mu = s_mu, rstd = s_rstd;
    float r0 = fmaxf((t0 - mu) * rstd * lng[j0] + lnb[j0], 0.f);
    vnrelu[(size_t)g * 320 + j0] = f2bf(r0);
    if (j1 < 320) {
        float r1 = g1 ? fmaxf((t1 - mu) * rstd * lng[j1] + lnb[j1], 0.f) : 0.f;
        vnrelu[(size_t)g * 320 + j1] = g1 ? f2bf(r1) : (unsigned short)0;
    }
}

extern "C" void kernel_launch(void* const* d_in, const int* in_sizes, int n_in,
                              void* d_out, int out_size, void* d_ws, size_t ws_size,
                              hipStream_t stream) {
    const int*   x_atom = (const int*)d_in[0];
    const int*   x_chir = (const int*)d_in[1];
    const int*   src    = (const int*)d_in[2];
    const int*   dst    = (const int*)d_in[3];
    const int*   ety    = (const int*)d_in[4];
    const int*   edir   = (const int*)d_in[5];
    const int*   batch  = (const int*)d_in[6];
    const float* emb1   = (const float*)d_in[7];
    const float* emb2   = (const float*)d_in[8];
    const float* e1     = (const float*)d_in[9];
    const float* e2     = (const float*)d_in[10];
    const float* w1     = (const float*)d_in[11];
    const float* b1     = (const float*)d_in[12];
    const float* w2     = (const float*)d_in[13];
    const float* b2     = (const float*)d_in[14];
    const float* bng    = (const float*)d_in[15];
    const float* bnb    = (const float*)d_in[16];
    const float* bnm    = (const float*)d_in[17];
    const float* bnv    = (const float*)d_in[18];
    const float* vne    = (const float*)d_in[19];
    const float* vw1    = (const float*)d_in[20];
    const float* vb1    = (const float*)d_in[21];
    const float* lng    = (const float*)d_in[22];
    const float* lnb    = (const float*)d_in[23];
    const float* vw2    = (const float*)d_in[24];
    const float* vb2    = (const float*)d_in[25];

    const int N = in_sizes[0];
    const int E = in_sizes[2];
    const int gx = (N + 63) / 64;
    const int Npad = gx * 64;
    const int nbN = (N + 255) / 256;
    const int nbG = (GG + 255) / 256;

    float* h = (float*)d_out;                                   // [N, D]

    // workspace layout (unchanged; 'hidden' region now unused)
    unsigned short* aggrb  = (unsigned short*)d_ws;                      // [Npad,320] bf16
    unsigned short* hidden = aggrb + (size_t)Npad * 320;                 // [Npad,640] bf16 (unused)
    short*          w1t    = (short*)(hidden + (size_t)Npad * 640);      // [L,640,320] bf16
    short*          w2t    = w1t + (size_t)LL * 640 * 320;               // [L,320,640] bf16
    short*          vw1t   = w2t + (size_t)LL * 320 * 640;               // [L-1,320,320] bf16
    short*          vw2t   = vw1t + (size_t)(LL - 1) * 320 * 320;        // [L-1,320,320] bf16
    unsigned short* vnin   = (unsigned short*)(vw2t + (size_t)(LL - 1) * 320 * 320); // [GPAD,320] bf16
    unsigned short* vnrelu = vnin + (size_t)GPAD * 320;                  // [GPAD,320] bf16
    float*          b1p    = (float*)(vnrelu + (size_t)GPAD * 320);      // [L,640]
    float*          comb   = b1p + (size_t)LL * 640;                     // [L,18,300]
    float*          tbuf   = comb + (size_t)LL * 18 * DD;                // [G,300]
    float*          vnh    = tbuf + (size_t)GG * DD;                     // [G,300]
    int*            deg    = (int*)(vnh + (size_t)GG * DD);              // [N]      } zeroed
    int*            cursor = deg + N;                                    // [N]      } as one
    int*            gcnt   = cursor + N;                                 // [G]      } memset
    int*            rowptr = gcnt + GG;                                  // [N+1]
    int*            gptr   = rowptr + (N + 1);                           // [G+1]
    int*            bsumN  = gptr + (GG + 1);                            // [nbN]
    int*            bsumG  = bsumN + 1024;                               // [nbG]
    int*            einfo  = bsumG + 1024;                               // [E]

    // --- weight prep ---
    k_convw<<<dim3(640, LL), 256, 0, stream>>>(w1, w1t, DD, DD2, 320, 640);
    k_convw<<<dim3(320, LL), 256, 0, stream>>>(w2, w2t, DD2, DD, 640, 320);
    k_convw<<<dim3(320, LL - 1), 256, 0, stream>>>(vw1, vw1t, DD, DD, 320, 320);
    k_convw<<<dim3(320, LL - 1), 256, 0, stream>>>(vw2, vw2t, DD, DD, 320, 320);
    k_padb<<<dim3(3, LL), 256, 0, stream>>>(b1, b1p);
    k_comb<<<dim3(18, LL), 256, 0, stream>>>(e1, e2, comb);

    // --- CSR (by dst) + graph ranges (batch sorted) ---
    hipMemsetAsync(deg, 0, (size_t)(2 * N + GG) * sizeof(int), stream);
    k_hist<<<(E + 255) / 256, 256, 0, stream>>>(dst, deg, E);
    k_hist<<<(N + 255) / 256, 256, 0, stream>>>(batch, gcnt, N);
    k_scan1<<<nbN, 256, 0, stream>>>(deg, bsumN, N);
    k_scan2<<<1, 1024, 0, stream>>>(bsumN, nbN);
    k_scan3<<<nbN, 256, 0, stream>>>(deg, bsumN, rowptr, N, E);
    k_scan1<<<nbG, 256, 0, stream>>>(gcnt, bsumG, GG);
    k_scan2<<<1, 1024, 0, stream>>>(bsumG, nbG);
    k_scan3<<<nbG, 256, 0, stream>>>(gcnt, bsumG, gptr, GG, N);
    k_place<<<(E + 255) / 256, 256, 0, stream>>>(src, dst, ety, edir, rowptr, cursor, einfo, E);

    k_init_h<<<N, 256, 0, stream>>>(x_atom, x_chir, emb1, emb2, vne, h, N);
    k_init_vn<<<GG, 256, 0, stream>>>(vne, vnh);

    for (int l = 0; l < LL; l++) {
        k_aggr<<<Npad / 4, 256, 0, stream>>>(h, rowptr, einfo, comb + (size_t)l * 18 * DD,
                                             batch, vnh, (l > 0) ? 1 : 0, aggrb, N, Npad);
        k_mlp<<<gx, 256, 0, stream>>>(aggrb, w1t + (size_t)l * 640 * 320,
                                      b1p + (size_t)l * 640,
                                      w2t + (size_t)l * 320 * 640,
                                      b2 + (size_t)l * DD,
                                      bng + (size_t)l * DD, bnb + (size_t)l * DD,
                                      bnm + (size_t)l * DD, bnv + (size_t)l * DD,
                                      h, N, (l < LL - 1) ? 1 : 0);
        if (l < LL - 1) {
            k_pool2<<<GG, 256, 0, stream>>>(h, gptr, vnh, vnin);
            k_vng<<<dim3(GPAD / 64, 2), 256, 0, stream>>>(vnin, vw1t + (size_t)l * 320 * 320,
                                                          vb1 + (size_t)l * DD, tbuf, GG);
            k_ln<<<GG, 256, 0, stream>>>(tbuf, lng + (size_t)l * DD, lnb + (size_t)l * DD, vnrelu);
            k_vng<<<dim3(GPAD / 64, 2), 256, 0, stream>>>(vnrelu, vw2t + (size_t)l * 320 * 320,
                                                          vb2 + (size_t)l * DD, vnh, GG);
        }
    }
}